// Round 7
// baseline (299.472 us; speedup 1.0000x reference)
//
#include <hip/hip_runtime.h>

#define NT    8192      // tokens (B*S)
#define DIM   1024      // d_model
#define NE    8         // experts
#define NH    512       // hidden
#define NROWS (NT*2)    // token-expert assignments (top_k=2)

typedef _Float16 f16;
typedef unsigned int u32;
typedef __attribute__((ext_vector_type(8))) _Float16 f16x8;
typedef __attribute__((ext_vector_type(4))) _Float16 f16x4;
typedef __attribute__((ext_vector_type(2))) _Float16 f16x2;
typedef __attribute__((ext_vector_type(4))) float f32x4;

// global -> LDS direct DMA, 16B per lane (wave-uniform base + lane*16).
__device__ __forceinline__ void gl2lds16(const f16* gptr, f16* ldsptr) {
    __builtin_amdgcn_global_load_lds(
        (const __attribute__((address_space(1))) u32*)gptr,
        (__attribute__((address_space(3))) u32*)ldsptr, 16, 0, 0);
}

// XOR-swizzled fragment read from unpadded [rows][32] f16 LDS.
#define FR(sbuf, row, q) \
    (*(const f16x8*)&sbuf[(row)*32 + (((q) ^ (((row) >> 1) & 3)) << 3)])

// ---------------- prep: router logits (blocks 0..1023) + weight transpose ----
#define KC 512
__global__ __launch_bounds__(256) void prep_kernel(
    const float* __restrict__ x, const float* __restrict__ wr,
    const float* __restrict__ w1, const float* __restrict__ w3,
    const float* __restrict__ w2, float* __restrict__ plogits,
    f16* __restrict__ w1t, f16* __restrict__ w3t, f16* __restrict__ w2t)
{
    __shared__ float smem[NE*KC];   // 16 KiB; transpose uses first 32*33 floats
    int tid = threadIdx.x;
    int bi = blockIdx.x;
    if (bi < 1024) {
        // ---- router logits, split-K: bx 0..511 (token tile), by 0..1 (K half)
        int bx = bi & 511, by = bi >> 9;
        int kc0 = by * KC;
        for (int i = tid; i < NE*KC; i += 256) {
            int k = i >> 3, e = i & 7;
            smem[e*KC + k] = wr[(size_t)kc0*NE + i];
        }
        __syncthreads();
        int tok = bx*16 + (tid >> 4);
        int kl  = tid & 15;
        float acc[NE];
        #pragma unroll
        for (int e = 0; e < NE; e++) acc[e] = 0.f;
        const float* xrow = x + (size_t)tok*DIM + kc0;
        #pragma unroll
        for (int i = 0; i < KC/64; i++) {
            int kb = i*64 + kl*4;
            float4 xv = *(const float4*)(xrow + kb);
            #pragma unroll
            for (int e = 0; e < NE; e++) {
                float4 wv = *(const float4*)&smem[e*KC + kb];
                acc[e] += xv.x*wv.x + xv.y*wv.y + xv.z*wv.z + xv.w*wv.w;
            }
        }
        #pragma unroll
        for (int e = 0; e < NE; e++) {
            float v = acc[e];
            v += __shfl_xor(v, 1); v += __shfl_xor(v, 2);
            v += __shfl_xor(v, 4); v += __shfl_xor(v, 8);
            acc[e] = v;
        }
        if (kl == 0) {
            float* pp = plogits + ((size_t)by*NT + tok)*NE;
            float4 o0 = {acc[0], acc[1], acc[2], acc[3]};
            float4 o1 = {acc[4], acc[5], acc[6], acc[7]};
            *(float4*)pp = o0;
            *(float4*)(pp + 4) = o1;
        }
    } else {
        // ---- fused transpose+cast of w1,w3,w2 (12288 blocks)
        int tz = bi - 1024;
        int zx = tz & 511, zy = tz >> 9;      // zx 0..511, zy 0..23
        int tensor = zy >> 3, e = zy & 7;
        const float* src; f16* dst; int R, C;
        if (tensor == 0)      { src = w1; dst = w1t; R = DIM; C = NH; }
        else if (tensor == 1) { src = w3; dst = w3t; R = DIM; C = NH; }
        else                  { src = w2; dst = w2t; R = NH; C = DIM; }
        src += (size_t)e * DIM * NH;
        dst += (size_t)e * DIM * NH;
        int tcols = C >> 5;
        int bx = zx % tcols, by = zx / tcols;
        int r0 = by*32, c0 = bx*32;
        int tx = tid & 31, ty = tid >> 5;
        #pragma unroll
        for (int i = ty; i < 32; i += 8)
            smem[i*33 + tx] = src[(size_t)(r0+i)*C + c0 + tx];
        __syncthreads();
        int p = tid & 15;
        #pragma unroll
        for (int pass = 0; pass < 2; pass++) {
            int i = (tid >> 4) + pass*16;
            f16x2 v = { (f16)smem[(2*p)*33 + i], (f16)smem[(2*p+1)*33 + i] };
            *(f16x2*)&dst[(size_t)(c0+i)*R + r0 + 2*p] = v;
        }
    }
}

// ---------------- finalize: softmax+top2 + hist + scan + ranked scatter ------
__global__ __launch_bounds__(1024) void finalize_kernel(
    const float* __restrict__ plogits, int* __restrict__ tok_ids,
    int* __restrict__ aid, float* __restrict__ row_gate, int* __restrict__ offs)
{
    __shared__ unsigned char s_e[NROWS];   // 16 KB
    __shared__ float s_w[NROWS];           // 64 KB
    __shared__ int hist[NE], cur[NE];
    int tid = threadIdx.x;
    if (tid < NE) hist[tid] = 0;
    __syncthreads();

    #pragma unroll 1
    for (int it = 0; it < NT/1024; it++) {
        int t = it*1024 + tid;
        const float* p0 = plogits + (size_t)t*NE;
        const float* p1 = plogits + (size_t)NT*NE + (size_t)t*NE;
        float4 a0 = *(const float4*)p0, a1 = *(const float4*)(p0+4);
        float4 b0 = *(const float4*)p1, b1 = *(const float4*)(p1+4);
        float l[NE] = { a0.x+b0.x, a0.y+b0.y, a0.z+b0.z, a0.w+b0.w,
                        a1.x+b1.x, a1.y+b1.y, a1.z+b1.z, a1.w+b1.w };
        float m = l[0];
        #pragma unroll
        for (int e = 1; e < NE; e++) m = fmaxf(m, l[e]);
        float s = 0.f;
        #pragma unroll
        for (int e = 0; e < NE; e++) { l[e] = __expf(l[e] - m); s += l[e]; }
        float inv = 1.f / s;
        int i0 = 0; float v0 = l[0];
        #pragma unroll
        for (int e = 1; e < NE; e++) if (l[e] > v0) { v0 = l[e]; i0 = e; }
        int i1 = -1; float v1 = -1.f;
        #pragma unroll
        for (int e = 0; e < NE; e++) if (e != i0 && l[e] > v1) { v1 = l[e]; i1 = e; }
        s_e[t*2+0] = (unsigned char)i0; s_w[t*2+0] = v0*inv;
        s_e[t*2+1] = (unsigned char)i1; s_w[t*2+1] = v1*inv;
        #pragma unroll
        for (int ee = 0; ee < NE; ee++) {
            int c = __popcll(__ballot(i0 == ee)) + __popcll(__ballot(i1 == ee));
            if ((tid & 63) == 0 && c) atomicAdd(&hist[ee], c);
        }
    }
    __syncthreads();

    if (tid == 0) {
        int s = 0;
        #pragma unroll
        for (int e = 0; e < NE; e++) { offs[e] = s; cur[e] = s; s += hist[e]; }
        offs[NE] = s;
    }
    __syncthreads();

    unsigned long long ltmask = (1ULL << (tid & 63)) - 1;
    #pragma unroll 1
    for (int it = 0; it < NROWS/1024; it++) {
        int id = it*1024 + tid;
        int e = s_e[id];
        int pos = 0;
        #pragma unroll
        for (int ee = 0; ee < NE; ee++) {
            unsigned long long mk = __ballot(e == ee);
            int cnt = __popcll(mk);
            int b = 0;
            if ((tid & 63) == 0 && cnt) b = atomicAdd(&cur[ee], cnt);
            b = __shfl(b, 0);
            if (e == ee) pos = b + __popcll(mk & ltmask);
        }
        tok_ids[pos] = id >> 1;
        aid[pos] = id;
        row_gate[pos] = s_w[id];
    }
}

// ---------------- grouped GEMM tiles ----------------
#define BK 32

// GEMM1: BM=64 x BN=128 tile; wave = 64x32 (acc 4x2 per GEMM -> 64 acc regs,
// 3 waves/SIMD). A (fp32 x) prefetched into regs across the MFMA section so
// its HBM latency is off the K-iter critical path; B1/B3 via DMA.
#define BM1 64
#define BN1 128
__global__ __launch_bounds__(256,3) void gemm1_kernel(
    const float* __restrict__ x, const int* __restrict__ tok_ids,
    const f16* __restrict__ w1t, const f16* __restrict__ w3t,
    f16* __restrict__ gbuf, const int* __restrict__ offs)
{
    int bi = blockIdx.x;
    int e  = bi & 7;
    int r_ = bi >> 3;
    int nt = r_ & 3;          // NH/BN1 = 4
    int mt = r_ >> 2;         // 0..255
    int off = offs[e];
    int n_e = offs[e+1] - off;
    if (mt*BM1 >= n_e) return;

    __shared__ f16 sA [BM1*32];   // 4 KB
    __shared__ f16 sB1[BN1*32];   // 8 KB
    __shared__ f16 sB3[BN1*32];   // 8 KB
    __shared__ int stok[BM1];

    int tid = threadIdx.x;
    if (tid < BM1) {
        int rloc = mt*BM1 + tid; rloc = rloc < n_e ? rloc : n_e - 1;
        stok[tid] = tok_ids[off + rloc];
    }
    __syncthreads();

    int lane = tid & 63, w = tid >> 6;
    int wcol = w*32;
    int q = lane >> 4, lm = lane & 15;

    // A staging (VGPR path): thread -> row rA, global granule gA
    int rA = tid >> 2, gA = tid & 3;
    const float* xr = x + (size_t)stok[rA]*DIM + gA*8;
    f16* sAp = &sA[rA*32 + ((gA ^ ((rA>>1)&3)) << 3)];

    // B staging (DMA): wave w covers rows [w*32, w*32+32)
    int rB0 = w*32 + (lane >> 2);
    int rB1 = rB0 + 16;
    int jB0 = (lane & 3) ^ ((rB0 >> 1) & 3);
    int jB1 = (lane & 3) ^ ((rB1 >> 1) & 3);
    const f16* w1p = w1t + ((size_t)e*NH + nt*BN1)*DIM;
    const f16* w3p = w3t + ((size_t)e*NH + nt*BN1)*DIM;
    const f16* pB1_0 = w1p + (size_t)rB0*DIM + jB0*8;
    const f16* pB1_1 = w1p + (size_t)rB1*DIM + jB1*8;
    const f16* pB3_0 = w3p + (size_t)rB0*DIM + jB0*8;
    const f16* pB3_1 = w3p + (size_t)rB1*DIM + jB1*8;
    f16* lB1_0 = &sB1[rB0*32 + ((lane & 3) << 3)];
    f16* lB1_1 = &sB1[rB1*32 + ((lane & 3) << 3)];
    f16* lB3_0 = &sB3[rB0*32 + ((lane & 3) << 3)];
    f16* lB3_1 = &sB3[rB1*32 + ((lane & 3) << 3)];

    f32x4 acc1[4][2], acc3[4][2];
    #pragma unroll
    for (int a = 0; a < 4; a++)
        #pragma unroll
        for (int b = 0; b < 2; b++) {
            acc1[a][b] = (f32x4){0.f,0.f,0.f,0.f};
            acc3[a][b] = (f32x4){0.f,0.f,0.f,0.f};
        }

    float4 a0 = *(const float4*)(xr);
    float4 a1 = *(const float4*)(xr + 4);

    for (int k0 = 0; k0 < DIM; k0 += BK) {
        __syncthreads();
        *(f16x8*)sAp = (f16x8){ (f16)a0.x,(f16)a0.y,(f16)a0.z,(f16)a0.w,
                                (f16)a1.x,(f16)a1.y,(f16)a1.z,(f16)a1.w };
        gl2lds16(pB1_0 + k0, lB1_0);
        gl2lds16(pB1_1 + k0, lB1_1);
        gl2lds16(pB3_0 + k0, lB3_0);
        gl2lds16(pB3_1 + k0, lB3_1);
        __syncthreads();   // drains DMA + ds_write
        if (k0 + BK < DIM) {    // prefetch next A during MFMA
            a0 = *(const float4*)(xr + k0 + BK);
            a1 = *(const float4*)(xr + k0 + BK + 4);
        }
        f16x8 aF[4], b1F[2], b3F[2];
        #pragma unroll
        for (int s = 0; s < 4; s++) aF[s] = FR(sA, s*16 + lm, q);
        #pragma unroll
        for (int c = 0; c < 2; c++) {
            b1F[c] = FR(sB1, wcol + c*16 + lm, q);
            b3F[c] = FR(sB3, wcol + c*16 + lm, q);
        }
        #pragma unroll
        for (int sr = 0; sr < 4; sr++)
            #pragma unroll
            for (int sc = 0; sc < 2; sc++) {
                acc1[sr][sc] = __builtin_amdgcn_mfma_f32_16x16x32_f16(aF[sr], b1F[sc], acc1[sr][sc], 0, 0, 0);
                acc3[sr][sc] = __builtin_amdgcn_mfma_f32_16x16x32_f16(aF[sr], b3F[sc], acc3[sr][sc], 0, 0, 0);
            }
    }
    // epilogue: silu(h1)*h3 -> f16 gbuf.  C/D: col=lane&15, row=(lane>>4)*4+reg
    #pragma unroll
    for (int sr = 0; sr < 4; sr++) {
        #pragma unroll
        for (int reg = 0; reg < 4; reg++) {
            int row = mt*BM1 + sr*16 + q*4 + reg;
            if (row < n_e) {
                #pragma unroll
                for (int sc = 0; sc < 2; sc++) {
                    int col = nt*BN1 + wcol + sc*16 + lm;
                    float g1 = acc1[sr][sc][reg];
                    float g3 = acc3[sr][sc][reg];
                    float gv = g1 / (1.f + __expf(-g1)) * g3;
                    gbuf[(size_t)(off + row)*NH + col] = (f16)gv;
                }
            }
        }
    }
}

// GEMM2: ybuf[aid[row]] = gate * (G @ W2). Full DMA staging. 128x128 tile.
#define BM 128
#define BN 128
__global__ __launch_bounds__(256,4) void gemm2_kernel(
    const f16* __restrict__ gbuf, const f16* __restrict__ w2t,
    const int* __restrict__ offs, const int* __restrict__ aid,
    const float* __restrict__ row_gate, f16* __restrict__ ybuf)
{
    int bi = blockIdx.x;
    int e  = bi & 7;
    int r_ = bi >> 3;
    int nt = r_ & 7;          // DIM/BN = 8
    int mt = r_ >> 3;
    int off = offs[e];
    int n_e = offs[e+1] - off;
    if (mt*BM >= n_e) return;

    __shared__ f16 sA[BM*32];
    __shared__ f16 sB[BN*32];
    __shared__ int said[BM];
    __shared__ float sgate[BM];

    int tid = threadIdx.x;
    if (tid < BM) {
        int rloc = mt*BM + tid;
        if (rloc < n_e) { said[tid] = aid[off + rloc]; sgate[tid] = row_gate[off + rloc]; }
        else            { said[tid] = 0; sgate[tid] = 0.f; }
    }

    int lane = tid & 63, w = tid >> 6;
    int wrow = (w >> 1)*64, wcol = (w & 1)*64;
    int q = lane >> 4, lm = lane & 15;

    int rB0 = w*32 + (lane >> 2);
    int rB1 = rB0 + 16;
    int jB0 = (lane & 3) ^ ((rB0 >> 1) & 3);
    int jB1 = (lane & 3) ^ ((rB1 >> 1) & 3);
    int ra0 = mt*BM + rB0; ra0 = ra0 < n_e ? ra0 : n_e - 1;
    int ra1 = mt*BM + rB1; ra1 = ra1 < n_e ? ra1 : n_e - 1;
    const f16* pA0 = gbuf + (size_t)(off + ra0)*NH + jB0*8;
    const f16* pA1 = gbuf + (size_t)(off + ra1)*NH + jB1*8;
    const f16* w2p = w2t + ((size_t)e*DIM + nt*BN)*NH;
    const f16* pB0 = w2p + (size_t)rB0*NH + jB0*8;
    const f16* pB1 = w2p + (size_t)rB1*NH + jB1*8;
    f16* lA0 = &sA[rB0*32 + ((lane & 3) << 3)];
    f16* lA1 = &sA[rB1*32 + ((lane & 3) << 3)];
    f16* lB0 = &sB[rB0*32 + ((lane & 3) << 3)];
    f16* lB1 = &sB[rB1*32 + ((lane & 3) << 3)];

    f32x4 acc[4][4];
    #pragma unroll
    for (int a = 0; a < 4; a++)
        #pragma unroll
        for (int b = 0; b < 4; b++) acc[a][b] = (f32x4){0.f,0.f,0.f,0.f};

    __syncthreads();   // covers said/sgate writes

    for (int k0 = 0; k0 < NH; k0 += BK) {
        gl2lds16(pA0 + k0, lA0);
        gl2lds16(pA1 + k0, lA1);
        gl2lds16(pB0 + k0, lB0);
        gl2lds16(pB1 + k0, lB1);
        __syncthreads();   // drains vmcnt
        f16x8 aF[4], bF[4];
        #pragma unroll
        for (int s = 0; s < 4; s++) {
            aF[s] = FR(sA, wrow + s*16 + lm, q);
            bF[s] = FR(sB, wcol + s*16 + lm, q);
        }
        #pragma unroll
        for (int sr = 0; sr < 4; sr++)
            #pragma unroll
            for (int sc = 0; sc < 4; sc++)
                acc[sr][sc] = __builtin_amdgcn_mfma_f32_16x16x32_f16(aF[sr], bF[sc], acc[sr][sc], 0, 0, 0);
        __syncthreads();   // reads done before next iter's DMA
    }
    #pragma unroll
    for (int sr = 0; sr < 4; sr++) {
        #pragma unroll
        for (int reg = 0; reg < 4; reg++) {
            int lrow = wrow + sr*16 + q*4 + reg;
            if (mt*BM + lrow < n_e) {
                int id = said[lrow];
                float wgt = sgate[lrow];
                #pragma unroll
                for (int sc = 0; sc < 4; sc++) {
                    int col = nt*BN + wcol + sc*16 + lm;
                    ybuf[(size_t)id*DIM + col] = (f16)(wgt * acc[sr][sc][reg]);
                }
            }
        }
    }
}

// ---------------- combine: out[t] = ybuf[2t] + ybuf[2t+1] ----------------
__global__ __launch_bounds__(256) void combine_kernel(
    const f16* __restrict__ ybuf, float* __restrict__ out)
{
    int gid = blockIdx.x*256 + threadIdx.x;
    int t = gid >> 7;
    int c = (gid & 127) << 3;
    f16x8 y0 = *(const f16x8*)(ybuf + ((size_t)2*t)*DIM + c);
    f16x8 y1 = *(const f16x8*)(ybuf + ((size_t)2*t+1)*DIM + c);
    float* op = out + (size_t)t*DIM + c;
    float4 o0 = { (float)y0[0] + (float)y1[0], (float)y0[1] + (float)y1[1],
                  (float)y0[2] + (float)y1[2], (float)y0[3] + (float)y1[3] };
    float4 o1 = { (float)y0[4] + (float)y1[4], (float)y0[5] + (float)y1[5],
                  (float)y0[6] + (float)y1[6], (float)y0[7] + (float)y1[7] };
    *(float4*)op = o0;
    *(float4*)(op + 4) = o1;
}

extern "C" void kernel_launch(void* const* d_in, const int* in_sizes, int n_in,
                              void* d_out, int out_size, void* d_ws, size_t ws_size,
                              hipStream_t stream)
{
    const float* x  = (const float*)d_in[0];
    const float* wr = (const float*)d_in[1];
    const float* w1 = (const float*)d_in[2];
    const float* w2 = (const float*)d_in[3];
    const float* w3 = (const float*)d_in[4];
    float* out = (float*)d_out;

    char* ws = (char*)d_ws;
    f16* ybuf    = (f16*)ws;        ws += (size_t)NROWS*DIM*sizeof(f16);   // 32 MiB (writer: gemm2)
    f16* w1t     = (f16*)ws;        ws += (size_t)NE*NH*DIM*sizeof(f16);   // 8 MiB (writer: prep)
    f16* w3t     = (f16*)ws;        ws += (size_t)NE*NH*DIM*sizeof(f16);   // 8 MiB (writer: prep)
    f16* w2t     = (f16*)ws;        ws += (size_t)NE*DIM*NH*sizeof(f16);   // 8 MiB (writer: prep)
    f16* gbuf    = (f16*)ws;        ws += (size_t)NROWS*NH*sizeof(f16);    // 16 MiB (writer: gemm1)
    float* plogits = (float*)ws;    ws += (size_t)2*NT*NE*4;               // 512 KiB (writer: prep)
    int* tok_ids = (int*)ws;        ws += (size_t)NROWS*4;                 // (writer: finalize)
    int* aid     = (int*)ws;        ws += (size_t)NROWS*4;
    float* row_gate = (float*)ws;   ws += (size_t)NROWS*4;
    int* offs    = (int*)ws;        ws += 64;
    if (ws_size < (size_t)(ws - (char*)d_ws)) return;  // ~72.7 MB needed

    prep_kernel<<<1024 + 12288, 256, 0, stream>>>(x, wr, w1, w3, w2,
                                                  plogits, w1t, w3t, w2t);
    finalize_kernel<<<1, 1024, 0, stream>>>(plogits, tok_ids, aid, row_gate, offs);
    gemm1_kernel<<<8192, 256, 0, stream>>>(x, tok_ids, w1t, w3t, gbuf, offs);
    gemm2_kernel<<<8192, 256, 0, stream>>>(gbuf, w2t, offs, aid, row_gate, ybuf);
    combine_kernel<<<(NT*(DIM/8))/256, 256, 0, stream>>>(ybuf, out);
}

// Round 8
// 271.371 us; speedup vs baseline: 1.1036x; 1.1036x over previous
//
#include <hip/hip_runtime.h>

#define NT    8192      // tokens (B*S)
#define DIM   1024      // d_model
#define NE    8         // experts
#define NH    512       // hidden
#define NROWS (NT*2)    // token-expert assignments (top_k=2)

typedef _Float16 f16;
typedef unsigned int u32;
typedef __attribute__((ext_vector_type(8))) _Float16 f16x8;
typedef __attribute__((ext_vector_type(4))) _Float16 f16x4;
typedef __attribute__((ext_vector_type(2))) _Float16 f16x2;
typedef __attribute__((ext_vector_type(4))) float f32x4;

// global -> LDS direct DMA, 16B per lane (wave-uniform base + lane*16).
__device__ __forceinline__ void gl2lds16(const f16* gptr, f16* ldsptr) {
    __builtin_amdgcn_global_load_lds(
        (const __attribute__((address_space(1))) u32*)gptr,
        (__attribute__((address_space(3))) u32*)ldsptr, 16, 0, 0);
}

// XOR-swizzled fragment read from unpadded [rows][32] f16 sub-tile
// (proven conflict-free in R6: SQ_LDS_BANK_CONFLICT == 0).
#define FR(sbuf, row, q) \
    (*(const f16x8*)&sbuf[(row)*32 + (((q) ^ (((row) >> 1) & 3)) << 3)])

// ---------------- prep: router logits (blocks 0..1023) + weight transpose ----
#define KC 512
__global__ __launch_bounds__(256) void prep_kernel(
    const float* __restrict__ x, const float* __restrict__ wr,
    const float* __restrict__ w1, const float* __restrict__ w3,
    const float* __restrict__ w2, float* __restrict__ plogits,
    f16* __restrict__ w1t, f16* __restrict__ w3t, f16* __restrict__ w2t)
{
    __shared__ float smem[NE*KC];   // 16 KiB; transpose uses first 32*33 floats
    int tid = threadIdx.x;
    int bi = blockIdx.x;
    if (bi < 1024) {
        int bx = bi & 511, by = bi >> 9;
        int kc0 = by * KC;
        for (int i = tid; i < NE*KC; i += 256) {
            int k = i >> 3, e = i & 7;
            smem[e*KC + k] = wr[(size_t)kc0*NE + i];
        }
        __syncthreads();
        int tok = bx*16 + (tid >> 4);
        int kl  = tid & 15;
        float acc[NE];
        #pragma unroll
        for (int e = 0; e < NE; e++) acc[e] = 0.f;
        const float* xrow = x + (size_t)tok*DIM + kc0;
        #pragma unroll
        for (int i = 0; i < KC/64; i++) {
            int kb = i*64 + kl*4;
            float4 xv = *(const float4*)(xrow + kb);
            #pragma unroll
            for (int e = 0; e < NE; e++) {
                float4 wv = *(const float4*)&smem[e*KC + kb];
                acc[e] += xv.x*wv.x + xv.y*wv.y + xv.z*wv.z + xv.w*wv.w;
            }
        }
        #pragma unroll
        for (int e = 0; e < NE; e++) {
            float v = acc[e];
            v += __shfl_xor(v, 1); v += __shfl_xor(v, 2);
            v += __shfl_xor(v, 4); v += __shfl_xor(v, 8);
            acc[e] = v;
        }
        if (kl == 0) {
            float* pp = plogits + ((size_t)by*NT + tok)*NE;
            float4 o0 = {acc[0], acc[1], acc[2], acc[3]};
            float4 o1 = {acc[4], acc[5], acc[6], acc[7]};
            *(float4*)pp = o0;
            *(float4*)(pp + 4) = o1;
        }
    } else {
        int tz = bi - 1024;
        int zx = tz & 511, zy = tz >> 9;
        int tensor = zy >> 3, e = zy & 7;
        const float* src; f16* dst; int R, C;
        if (tensor == 0)      { src = w1; dst = w1t; R = DIM; C = NH; }
        else if (tensor == 1) { src = w3; dst = w3t; R = DIM; C = NH; }
        else                  { src = w2; dst = w2t; R = NH; C = DIM; }
        src += (size_t)e * DIM * NH;
        dst += (size_t)e * DIM * NH;
        int tcols = C >> 5;
        int bx = zx % tcols, by = zx / tcols;
        int r0 = by*32, c0 = bx*32;
        int tx = tid & 31, ty = tid >> 5;
        #pragma unroll
        for (int i = ty; i < 32; i += 8)
            smem[i*33 + tx] = src[(size_t)(r0+i)*C + c0 + tx];
        __syncthreads();
        int p = tid & 15;
        #pragma unroll
        for (int pass = 0; pass < 2; pass++) {
            int i = (tid >> 4) + pass*16;
            f16x2 v = { (f16)smem[(2*p)*33 + i], (f16)smem[(2*p+1)*33 + i] };
            *(f16x2*)&dst[(size_t)(c0+i)*R + r0 + 2*p] = v;
        }
    }
}

// ---------------- finalize: softmax+top2 + hist + scan + ranked scatter ------
__global__ __launch_bounds__(1024) void finalize_kernel(
    const float* __restrict__ plogits, int* __restrict__ tok_ids,
    int* __restrict__ aid, float* __restrict__ row_gate, int* __restrict__ offs)
{
    __shared__ unsigned char s_e[NROWS];   // 16 KB
    __shared__ float s_w[NROWS];           // 64 KB
    __shared__ int hist[NE], cur[NE];
    int tid = threadIdx.x;
    if (tid < NE) hist[tid] = 0;
    __syncthreads();

    #pragma unroll 1
    for (int it = 0; it < NT/1024; it++) {
        int t = it*1024 + tid;
        const float* p0 = plogits + (size_t)t*NE;
        const float* p1 = plogits + (size_t)NT*NE + (size_t)t*NE;
        float4 a0 = *(const float4*)p0, a1 = *(const float4*)(p0+4);
        float4 b0 = *(const float4*)p1, b1 = *(const float4*)(p1+4);
        float l[NE] = { a0.x+b0.x, a0.y+b0.y, a0.z+b0.z, a0.w+b0.w,
                        a1.x+b1.x, a1.y+b1.y, a1.z+b1.z, a1.w+b1.w };
        float m = l[0];
        #pragma unroll
        for (int e = 1; e < NE; e++) m = fmaxf(m, l[e]);
        float s = 0.f;
        #pragma unroll
        for (int e = 0; e < NE; e++) { l[e] = __expf(l[e] - m); s += l[e]; }
        float inv = 1.f / s;
        int i0 = 0; float v0 = l[0];
        #pragma unroll
        for (int e = 1; e < NE; e++) if (l[e] > v0) { v0 = l[e]; i0 = e; }
        int i1 = -1; float v1 = -1.f;
        #pragma unroll
        for (int e = 0; e < NE; e++) if (e != i0 && l[e] > v1) { v1 = l[e]; i1 = e; }
        s_e[t*2+0] = (unsigned char)i0; s_w[t*2+0] = v0*inv;
        s_e[t*2+1] = (unsigned char)i1; s_w[t*2+1] = v1*inv;
        #pragma unroll
        for (int ee = 0; ee < NE; ee++) {
            int c = __popcll(__ballot(i0 == ee)) + __popcll(__ballot(i1 == ee));
            if ((tid & 63) == 0 && c) atomicAdd(&hist[ee], c);
        }
    }
    __syncthreads();

    if (tid == 0) {
        int s = 0;
        #pragma unroll
        for (int e = 0; e < NE; e++) { offs[e] = s; cur[e] = s; s += hist[e]; }
        offs[NE] = s;
    }
    __syncthreads();

    unsigned long long ltmask = (1ULL << (tid & 63)) - 1;
    #pragma unroll 1
    for (int it = 0; it < NROWS/1024; it++) {
        int id = it*1024 + tid;
        int e = s_e[id];
        int pos = 0;
        #pragma unroll
        for (int ee = 0; ee < NE; ee++) {
            unsigned long long mk = __ballot(e == ee);
            int cnt = __popcll(mk);
            int b = 0;
            if ((tid & 63) == 0 && cnt) b = atomicAdd(&cur[ee], cnt);
            b = __shfl(b, 0);
            if (e == ee) pos = b + __popcll(mk & ltmask);
        }
        tok_ids[pos] = id >> 1;
        aid[pos] = id;
        row_gate[pos] = s_w[id];
    }
}

// ---------------- grouped GEMM tiles ----------------
// BK=64 as two 32-wide sub-tiles (layout identical to the proven R6 scheme).
#define BK 64

// GEMM1: BM=64 x BN=128; 16 K-iterations (halved barrier-drain count).
#define BM1 64
#define BN1 128
__global__ __launch_bounds__(256,3) void gemm1_kernel(
    const float* __restrict__ x, const int* __restrict__ tok_ids,
    const f16* __restrict__ w1t, const f16* __restrict__ w3t,
    f16* __restrict__ gbuf, const int* __restrict__ offs)
{
    int bi = blockIdx.x;
    int e  = bi & 7;
    int r_ = bi >> 3;
    int nt = r_ & 3;          // NH/BN1 = 4
    int mt = r_ >> 2;
    int off = offs[e];
    int n_e = offs[e+1] - off;
    if (mt*BM1 >= n_e) return;

    __shared__ f16 sA [2][BM1*32];   // 8 KB
    __shared__ f16 sB1[2][BN1*32];   // 16 KB
    __shared__ f16 sB3[2][BN1*32];   // 16 KB
    __shared__ int stok[BM1];

    int tid = threadIdx.x;
    if (tid < BM1) {
        int rloc = mt*BM1 + tid; rloc = rloc < n_e ? rloc : n_e - 1;
        stok[tid] = tok_ids[off + rloc];
    }
    __syncthreads();

    int lane = tid & 63, w = tid >> 6;
    int wcol = w*32;
    int q = lane >> 4, lm = lane & 15;

    // A staging (VGPR path): thread -> row rA, granule gA of both sub-tiles
    int rA = tid >> 2, gA = tid & 3;
    const float* xr = x + (size_t)stok[rA]*DIM + gA*8;
    int pA = (gA ^ ((rA>>1)&3)) << 3;
    f16* sA0p = &sA[0][rA*32 + pA];
    f16* sA1p = &sA[1][rA*32 + pA];

    // B staging (DMA): wave w covers rows [w*32, w*32+32) in 2 chunks of 16
    int lr0 = w*32 + (lane >> 2);
    int lr1 = lr0 + 16;
    int g0 = (lane & 3) ^ ((lr0 >> 1) & 3);
    int g1 = (lane & 3) ^ ((lr1 >> 1) & 3);
    const f16* w1p = w1t + ((size_t)e*NH + nt*BN1)*DIM;
    const f16* w3p = w3t + ((size_t)e*NH + nt*BN1)*DIM;
    const f16* pB1_0 = w1p + (size_t)lr0*DIM + g0*8;
    const f16* pB1_1 = w1p + (size_t)lr1*DIM + g1*8;
    const f16* pB3_0 = w3p + (size_t)lr0*DIM + g0*8;
    const f16* pB3_1 = w3p + (size_t)lr1*DIM + g1*8;
    int lofs0 = lr0*32 + ((lane & 3) << 3);
    int lofs1 = lr1*32 + ((lane & 3) << 3);

    f32x4 acc1[4][2], acc3[4][2];
    #pragma unroll
    for (int a = 0; a < 4; a++)
        #pragma unroll
        for (int b = 0; b < 2; b++) {
            acc1[a][b] = (f32x4){0.f,0.f,0.f,0.f};
            acc3[a][b] = (f32x4){0.f,0.f,0.f,0.f};
        }

    float4 a00 = *(const float4*)(xr);
    float4 a01 = *(const float4*)(xr + 4);
    float4 a10 = *(const float4*)(xr + 32);
    float4 a11 = *(const float4*)(xr + 36);

    for (int k0 = 0; k0 < DIM; k0 += BK) {
        __syncthreads();
        *(f16x8*)sA0p = (f16x8){ (f16)a00.x,(f16)a00.y,(f16)a00.z,(f16)a00.w,
                                 (f16)a01.x,(f16)a01.y,(f16)a01.z,(f16)a01.w };
        *(f16x8*)sA1p = (f16x8){ (f16)a10.x,(f16)a10.y,(f16)a10.z,(f16)a10.w,
                                 (f16)a11.x,(f16)a11.y,(f16)a11.z,(f16)a11.w };
        gl2lds16(pB1_0 + k0,      &sB1[0][lofs0]);
        gl2lds16(pB1_1 + k0,      &sB1[0][lofs1]);
        gl2lds16(pB1_0 + k0 + 32, &sB1[1][lofs0]);
        gl2lds16(pB1_1 + k0 + 32, &sB1[1][lofs1]);
        gl2lds16(pB3_0 + k0,      &sB3[0][lofs0]);
        gl2lds16(pB3_1 + k0,      &sB3[0][lofs1]);
        gl2lds16(pB3_0 + k0 + 32, &sB3[1][lofs0]);
        gl2lds16(pB3_1 + k0 + 32, &sB3[1][lofs1]);
        __syncthreads();   // drains DMA + ds_write
        if (k0 + BK < DIM) {    // prefetch next A during MFMA section
            a00 = *(const float4*)(xr + k0 + BK);
            a01 = *(const float4*)(xr + k0 + BK + 4);
            a10 = *(const float4*)(xr + k0 + BK + 32);
            a11 = *(const float4*)(xr + k0 + BK + 36);
        }
        #pragma unroll
        for (int ks = 0; ks < 2; ks++) {
            f16x8 aF[4], b1F[2], b3F[2];
            #pragma unroll
            for (int s = 0; s < 4; s++) aF[s] = FR(sA[ks], s*16 + lm, q);
            #pragma unroll
            for (int c = 0; c < 2; c++) {
                b1F[c] = FR(sB1[ks], wcol + c*16 + lm, q);
                b3F[c] = FR(sB3[ks], wcol + c*16 + lm, q);
            }
            #pragma unroll
            for (int sr = 0; sr < 4; sr++)
                #pragma unroll
                for (int sc = 0; sc < 2; sc++) {
                    acc1[sr][sc] = __builtin_amdgcn_mfma_f32_16x16x32_f16(aF[sr], b1F[sc], acc1[sr][sc], 0, 0, 0);
                    acc3[sr][sc] = __builtin_amdgcn_mfma_f32_16x16x32_f16(aF[sr], b3F[sc], acc3[sr][sc], 0, 0, 0);
                }
        }
    }
    // epilogue: silu(h1)*h3 -> f16 gbuf.  C/D: col=lane&15, row=(lane>>4)*4+reg
    #pragma unroll
    for (int sr = 0; sr < 4; sr++) {
        #pragma unroll
        for (int reg = 0; reg < 4; reg++) {
            int row = mt*BM1 + sr*16 + q*4 + reg;
            if (row < n_e) {
                #pragma unroll
                for (int sc = 0; sc < 2; sc++) {
                    int col = nt*BN1 + wcol + sc*16 + lm;
                    float h1 = acc1[sr][sc][reg];
                    float h3 = acc3[sr][sc][reg];
                    float gv = h1 / (1.f + __expf(-h1)) * h3;
                    gbuf[(size_t)(off + row)*NH + col] = (f16)gv;
                }
            }
        }
    }
}

// GEMM2: ybuf[aid[row]] = gate * (G @ W2). Full DMA staging, BK=64, 8 iters.
#define BM 128
#define BN 128
__global__ __launch_bounds__(256,3) void gemm2_kernel(
    const f16* __restrict__ gbuf, const f16* __restrict__ w2t,
    const int* __restrict__ offs, const int* __restrict__ aid,
    const float* __restrict__ row_gate, f16* __restrict__ ybuf)
{
    int bi = blockIdx.x;
    int e  = bi & 7;
    int r_ = bi >> 3;
    int nt = r_ & 7;          // DIM/BN = 8
    int mt = r_ >> 3;
    int off = offs[e];
    int n_e = offs[e+1] - off;
    if (mt*BM >= n_e) return;

    __shared__ f16 sA[2][BM*32];   // 16 KB
    __shared__ f16 sB[2][BN*32];   // 16 KB
    __shared__ int said[BM];
    __shared__ float sgate[BM];

    int tid = threadIdx.x;
    if (tid < BM) {
        int rloc = mt*BM + tid;
        if (rloc < n_e) { said[tid] = aid[off + rloc]; sgate[tid] = row_gate[off + rloc]; }
        else            { said[tid] = 0; sgate[tid] = 0.f; }
    }

    int lane = tid & 63, w = tid >> 6;
    int wrow = (w >> 1)*64, wcol = (w & 1)*64;
    int q = lane >> 4, lm = lane & 15;

    int lr0 = w*32 + (lane >> 2);
    int lr1 = lr0 + 16;
    int g0 = (lane & 3) ^ ((lr0 >> 1) & 3);
    int g1 = (lane & 3) ^ ((lr1 >> 1) & 3);
    int ga0 = mt*BM + lr0; ga0 = ga0 < n_e ? ga0 : n_e - 1;
    int ga1 = mt*BM + lr1; ga1 = ga1 < n_e ? ga1 : n_e - 1;
    const f16* pA0 = gbuf + (size_t)(off + ga0)*NH + g0*8;
    const f16* pA1 = gbuf + (size_t)(off + ga1)*NH + g1*8;
    const f16* w2p = w2t + ((size_t)e*DIM + nt*BN)*NH;
    const f16* pB0 = w2p + (size_t)lr0*NH + g0*8;
    const f16* pB1 = w2p + (size_t)lr1*NH + g1*8;
    int lofs0 = lr0*32 + ((lane & 3) << 3);
    int lofs1 = lr1*32 + ((lane & 3) << 3);

    f32x4 acc[4][4];
    #pragma unroll
    for (int a = 0; a < 4; a++)
        #pragma unroll
        for (int b = 0; b < 4; b++) acc[a][b] = (f32x4){0.f,0.f,0.f,0.f};

    __syncthreads();   // covers said/sgate writes

    for (int k0 = 0; k0 < NH; k0 += BK) {
        gl2lds16(pA0 + k0,      &sA[0][lofs0]);
        gl2lds16(pA1 + k0,      &sA[0][lofs1]);
        gl2lds16(pA0 + k0 + 32, &sA[1][lofs0]);
        gl2lds16(pA1 + k0 + 32, &sA[1][lofs1]);
        gl2lds16(pB0 + k0,      &sB[0][lofs0]);
        gl2lds16(pB1 + k0,      &sB[0][lofs1]);
        gl2lds16(pB0 + k0 + 32, &sB[1][lofs0]);
        gl2lds16(pB1 + k0 + 32, &sB[1][lofs1]);
        __syncthreads();   // drains vmcnt
        #pragma unroll
        for (int ks = 0; ks < 2; ks++) {
            f16x8 aF[4], bF[4];
            #pragma unroll
            for (int s = 0; s < 4; s++) {
                aF[s] = FR(sA[ks], wrow + s*16 + lm, q);
                bF[s] = FR(sB[ks], wcol + s*16 + lm, q);
            }
            #pragma unroll
            for (int sr = 0; sr < 4; sr++)
                #pragma unroll
                for (int sc = 0; sc < 4; sc++)
                    acc[sr][sc] = __builtin_amdgcn_mfma_f32_16x16x32_f16(aF[sr], bF[sc], acc[sr][sc], 0, 0, 0);
        }
        __syncthreads();   // reads done before next iter's DMA
    }
    #pragma unroll
    for (int sr = 0; sr < 4; sr++) {
        #pragma unroll
        for (int reg = 0; reg < 4; reg++) {
            int lrow = wrow + sr*16 + q*4 + reg;
            if (mt*BM + lrow < n_e) {
                int id = said[lrow];
                float wgt = sgate[lrow];
                #pragma unroll
                for (int sc = 0; sc < 4; sc++) {
                    int col = nt*BN + wcol + sc*16 + lm;
                    ybuf[(size_t)id*DIM + col] = (f16)(wgt * acc[sr][sc][reg]);
                }
            }
        }
    }
}

// ---------------- combine: out[t] = ybuf[2t] + ybuf[2t+1] ----------------
__global__ __launch_bounds__(256) void combine_kernel(
    const f16* __restrict__ ybuf, float* __restrict__ out)
{
    int gid = blockIdx.x*256 + threadIdx.x;
    int t = gid >> 7;
    int c = (gid & 127) << 3;
    f16x8 y0 = *(const f16x8*)(ybuf + ((size_t)2*t)*DIM + c);
    f16x8 y1 = *(const f16x8*)(ybuf + ((size_t)2*t+1)*DIM + c);
    float* op = out + (size_t)t*DIM + c;
    float4 o0 = { (float)y0[0] + (float)y1[0], (float)y0[1] + (float)y1[1],
                  (float)y0[2] + (float)y1[2], (float)y0[3] + (float)y1[3] };
    float4 o1 = { (float)y0[4] + (float)y1[4], (float)y0[5] + (float)y1[5],
                  (float)y0[6] + (float)y1[6], (float)y0[7] + (float)y1[7] };
    *(float4*)op = o0;
    *(float4*)(op + 4) = o1;
}

extern "C" void kernel_launch(void* const* d_in, const int* in_sizes, int n_in,
                              void* d_out, int out_size, void* d_ws, size_t ws_size,
                              hipStream_t stream)
{
    const float* x  = (const float*)d_in[0];
    const float* wr = (const float*)d_in[1];
    const float* w1 = (const float*)d_in[2];
    const float* w2 = (const float*)d_in[3];
    const float* w3 = (const float*)d_in[4];
    float* out = (float*)d_out;

    char* ws = (char*)d_ws;
    f16* ybuf    = (f16*)ws;        ws += (size_t)NROWS*DIM*sizeof(f16);   // 32 MiB (writer: gemm2)
    f16* w1t     = (f16*)ws;        ws += (size_t)NE*NH*DIM*sizeof(f16);   // 8 MiB (writer: prep)
    f16* w3t     = (f16*)ws;        ws += (size_t)NE*NH*DIM*sizeof(f16);   // 8 MiB (writer: prep)
    f16* w2t     = (f16*)ws;        ws += (size_t)NE*DIM*NH*sizeof(f16);   // 8 MiB (writer: prep)
    f16* gbuf    = (f16*)ws;        ws += (size_t)NROWS*NH*sizeof(f16);    // 16 MiB (writer: gemm1)
    float* plogits = (float*)ws;    ws += (size_t)2*NT*NE*4;               // 512 KiB (writer: prep)
    int* tok_ids = (int*)ws;        ws += (size_t)NROWS*4;                 // (writer: finalize)
    int* aid     = (int*)ws;        ws += (size_t)NROWS*4;
    float* row_gate = (float*)ws;   ws += (size_t)NROWS*4;
    int* offs    = (int*)ws;        ws += 64;
    if (ws_size < (size_t)(ws - (char*)d_ws)) return;  // ~72.7 MB needed

    prep_kernel<<<1024 + 12288, 256, 0, stream>>>(x, wr, w1, w3, w2,
                                                  plogits, w1t, w3t, w2t);
    finalize_kernel<<<1, 1024, 0, stream>>>(plogits, tok_ids, aid, row_gate, offs);
    gemm1_kernel<<<8192, 256, 0, stream>>>(x, tok_ids, w1t, w3t, gbuf, offs);
    gemm2_kernel<<<8192, 256, 0, stream>>>(gbuf, w2t, offs, aid, row_gate, ybuf);
    combine_kernel<<<(NT*(DIM/8))/256, 256, 0, stream>>>(ybuf, out);
}